// Round 1
// baseline (634.984 us; speedup 1.0000x reference)
//
#include <hip/hip_runtime.h>
#include <cstdint>

#define B_   8
#define N_   4096
#define E_   1024
#define H_   16
#define NFFT 2049

typedef unsigned short u16;
typedef unsigned int   u32;
typedef __attribute__((ext_vector_type(4))) float f32x4;
typedef __attribute__((ext_vector_type(8))) short short8;

__device__ __forceinline__ u16 f2bf(float f) {
    u32 u = __builtin_bit_cast(u32, f);
    u += 0x7fffu + ((u >> 16) & 1u);
    return (u16)(u >> 16);
}
__device__ __forceinline__ float bf2f(u16 h) {
    u32 u = ((u32)h) << 16;
    return __builtin_bit_cast(float, u);
}

// ---------------------------------------------------------------------------
// Kernel 1: x f32 -> bf16, fused column-mean partial sums (atomics into xbar)
// grid (64, B), 256 threads. Each block: 64 rows x 1024 cols.
// ---------------------------------------------------------------------------
__global__ __launch_bounds__(256)
void conv_x_kernel(const float* __restrict__ x, u16* __restrict__ xbf,
                   float* __restrict__ xbar)
{
    const int b  = blockIdx.y;
    const int n0 = blockIdx.x * 64;
    const int t  = threadIdx.x;
    const float4* src = (const float4*)(x + ((size_t)(b * N_ + n0)) * E_) + t;
    u16* dst = xbf + ((size_t)(b * N_ + n0)) * E_ + t * 4;
    float4 s = make_float4(0.f, 0.f, 0.f, 0.f);
    for (int r = 0; r < 64; r++) {
        float4 v = src[r * 256];
        s.x += v.x; s.y += v.y; s.z += v.z; s.w += v.w;
        *(ushort4*)(dst + (size_t)r * E_) =
            make_ushort4(f2bf(v.x), f2bf(v.y), f2bf(v.z), f2bf(v.w));
    }
    float* xb = xbar + b * E_ + t * 4;
    atomicAdd(xb + 0, s.x); atomicAdd(xb + 1, s.y);
    atomicAdd(xb + 2, s.z); atomicAdd(xb + 3, s.w);
}

// ---------------------------------------------------------------------------
// Kernel 2: f32 -> bf16 weight convert (1M elements)
// ---------------------------------------------------------------------------
__global__ __launch_bounds__(256)
void convw_kernel(const float* __restrict__ w, u16* __restrict__ wbf, int n4)
{
    int i = blockIdx.x * 256 + threadIdx.x;
    if (i >= n4) return;
    float4 v = ((const float4*)w)[i];
    *(ushort4*)(wbf + (size_t)i * 4) =
        make_ushort4(f2bf(v.x), f2bf(v.y), f2bf(v.z), f2bf(v.w));
}

// ---------------------------------------------------------------------------
// Kernel 3: gate MLP. One block per (b,h). bar_q = (mean_n x)@Wq^T row-slice,
// LayerNorm(D=64) -> silu(w1) -> w2 -> complex gate / 4096, Im(DC)=Im(Nyq)=0.
// ---------------------------------------------------------------------------
__global__ __launch_bounds__(256)
void gate_kernel(const float* __restrict__ xbar, const float* __restrict__ Wq,
                 const float* __restrict__ ln_g, const float* __restrict__ ln_b,
                 const float* __restrict__ w1,   const float* __restrict__ b1,
                 const float* __restrict__ w2,   const float* __restrict__ b2,
                 float* __restrict__ gate)
{
    const int bh = blockIdx.x;
    const int b = bh >> 4, h = bh & 15;
    const int t = threadIdx.x;
    __shared__ float s_x[1024];
    __shared__ float s_bq[64], s_ln[64], s_h1[64];

    for (int q = 0; q < 4; q++)
        s_x[(q << 8) + t] = xbar[b * 1024 + (q << 8) + t] * (1.0f / 4096.0f);
    __syncthreads();

    {   // bar_q[d] : 4 threads per d
        const int d = t >> 2, part = t & 3;
        const float* wrow = Wq + (size_t)(h * 64 + d) * 1024 + part * 256;
        const float* xr = s_x + part * 256;
        float sum = 0.f;
        #pragma unroll 8
        for (int e = 0; e < 256; e++) sum += wrow[e] * xr[e];
        sum += __shfl_xor(sum, 1);
        sum += __shfl_xor(sum, 2);
        if (part == 0) s_bq[d] = sum;
    }
    __syncthreads();

    if (t < 64) {  // LayerNorm over D=64 in wave 0
        float v = s_bq[t];
        float s = v;
        #pragma unroll
        for (int m = 1; m < 64; m <<= 1) s += __shfl_xor(s, m);
        float mu = s * (1.0f / 64.0f);
        float dv = v - mu;
        float vv = dv * dv;
        #pragma unroll
        for (int m = 1; m < 64; m <<= 1) vv += __shfl_xor(vv, m);
        float var = vv * (1.0f / 64.0f);
        s_ln[t] = dv * rsqrtf(var + 1e-5f) * ln_g[t] + ln_b[t];
    }
    __syncthreads();

    {   // h1 = silu(w1 @ ln + b1)
        const int j = t >> 2, part = t & 3;
        const float* wrow = w1 + j * 64 + part * 16;
        const float* lr = s_ln + part * 16;
        float sum = 0.f;
        #pragma unroll
        for (int d2 = 0; d2 < 16; d2++) sum += wrow[d2] * lr[d2];
        sum += __shfl_xor(sum, 1);
        sum += __shfl_xor(sum, 2);
        if (part == 0) {
            float z = sum + b1[j];
            s_h1[j] = z / (1.0f + __expf(-z));
        }
    }
    __syncthreads();

    float* grow = gate + (size_t)bh * (2 * NFFT);
    for (int o = t; o < 2 * NFFT; o += 256) {
        const float4* wrow = (const float4*)(w2 + (size_t)o * 64);
        float sum = 0.f;
        #pragma unroll
        for (int d4 = 0; d4 < 16; d4++) {
            float4 wv = wrow[d4];
            sum += wv.x * s_h1[d4 * 4]     + wv.y * s_h1[d4 * 4 + 1]
                 + wv.z * s_h1[d4 * 4 + 2] + wv.w * s_h1[d4 * 4 + 3];
        }
        float gv = (sum + b2[o]) * (1.0f / 4096.0f);   // fold irfft 1/N
        if (o == 1 || o == 2 * NFFT - 1) gv = 0.0f;    // Im(DC), Im(Nyquist)
        grow[o] = gv;
    }
}

// ---------------------------------------------------------------------------
// Kernel 4: bf16 MFMA GEMM, C[m,n] = sum_k A[m,k]*BT[n,k]
// 128x128 tile, BK=32, 4 waves (each 64x64), reg-staged LDS, inline-asm MFMA.
// OUTMODE 0: f32, row-major C (ld = N)
// OUTMODE 1: bf16, C written to vt[b][m][n&4095] with b = n>>12 (M must be 1024)
// ---------------------------------------------------------------------------
template<int OUTMODE>
__global__ __launch_bounds__(256)
void gemm_bt(const u16* __restrict__ A, const u16* __restrict__ BT,
             void* __restrict__ Cv, int M, int N, int K)
{
    __shared__ __align__(16) u16 lA[128 * 32];
    __shared__ __align__(16) u16 lB[128 * 32];
    const int tid = threadIdx.x;
    const int w = tid >> 6, l = tid & 63;
    const int m0 = blockIdx.y * 128, n0 = blockIdx.x * 128;
    const int wr = (w >> 1) * 64, wc = (w & 1) * 64;
    const int srow = w * 16 + (l >> 2);
    const int scol = (l & 3) * 8;
    const u16* ga = A  + (size_t)(m0 + srow) * K + scol;
    const u16* gb = BT + (size_t)(n0 + srow) * K + scol;
    char* lac = (char*)lA;
    char* lbc = (char*)lB;
    f32x4 acc[4][4] = {};

    short8 ra0 = *(const short8*)(ga);
    short8 ra1 = *(const short8*)(ga + (size_t)64 * K);
    short8 rb0 = *(const short8*)(gb);
    short8 rb1 = *(const short8*)(gb + (size_t)64 * K);

    for (int k0 = 0; k0 < K; k0 += 32) {
        __syncthreads();
        *(short8*)(lac +        w * 1024 + l * 16) = ra0;
        *(short8*)(lac + 4096 + w * 1024 + l * 16) = ra1;
        *(short8*)(lbc +        w * 1024 + l * 16) = rb0;
        *(short8*)(lbc + 4096 + w * 1024 + l * 16) = rb1;
        if (k0 + 32 < K) {   // prefetch next K-tile into regs (overlaps MFMA)
            ra0 = *(const short8*)(ga + k0 + 32);
            ra1 = *(const short8*)(ga + (size_t)64 * K + k0 + 32);
            rb0 = *(const short8*)(gb + k0 + 32);
            rb1 = *(const short8*)(gb + (size_t)64 * K + k0 + 32);
        }
        __syncthreads();
        short8 af[4], bfr[4];
        #pragma unroll
        for (int i = 0; i < 4; i++) {
            af[i]  = *(const short8*)(lac + (wr + i * 16 + (l & 15)) * 64 + (l >> 4) * 16);
            bfr[i] = *(const short8*)(lbc + (wc + i * 16 + (l & 15)) * 64 + (l >> 4) * 16);
        }
        #pragma unroll
        for (int i = 0; i < 4; i++)
            #pragma unroll
            for (int j2 = 0; j2 < 4; j2++)
                asm("v_mfma_f32_16x16x32_bf16 %0, %1, %2, %0"
                    : "+v"(acc[i][j2]) : "v"(af[i]), "v"(bfr[j2]));
    }

    const int fr = (l >> 4) * 4;   // C/D: row=(lane>>4)*4+reg, col=lane&15
    const int fc = l & 15;
    if (OUTMODE == 0) {
        float* C = (float*)Cv;
        #pragma unroll
        for (int i = 0; i < 4; i++) {
            int m = m0 + wr + i * 16 + fr;
            #pragma unroll
            for (int j2 = 0; j2 < 4; j2++) {
                int gn = n0 + wc + j2 * 16 + fc;
                #pragma unroll
                for (int r = 0; r < 4; r++)
                    C[(size_t)(m + r) * N + gn] = acc[i][j2][r];
            }
        }
    } else {
        u16* Cb = (u16*)Cv;
        #pragma unroll
        for (int i = 0; i < 4; i++) {
            int m = m0 + wr + i * 16 + fr;
            #pragma unroll
            for (int j2 = 0; j2 < 4; j2++) {
                int gn = n0 + wc + j2 * 16 + fc;
                int bb = gn >> 12, nin = gn & 4095;
                size_t base = ((size_t)bb << 22) + (size_t)nin;
                #pragma unroll
                for (int r = 0; r < 4; r++)
                    Cb[base + (size_t)(m + r) * 4096] = f2bf(acc[i][j2][r]);
            }
        }
    }
}

// ---------------------------------------------------------------------------
// Kernel 5: packed-pair FFT conv. One block per (b, h, d-pair).
// Radix-4 Stockham, 6 stages, LDS ping-pong; G Hermitian-extended gate.
// ---------------------------------------------------------------------------
__device__ __forceinline__ float2 cmul(float2 a, float2 b) {
    return make_float2(a.x * b.x - a.y * b.y, a.x * b.y + a.y * b.x);
}
__device__ __forceinline__ float2 cadd(float2 a, float2 b) {
    return make_float2(a.x + b.x, a.y + b.y);
}
__device__ __forceinline__ float2 csub(float2 a, float2 b) {
    return make_float2(a.x - b.x, a.y - b.y);
}

template<int SIGN>
__device__ __forceinline__ void fft6(float2* A, float2* B, int t)
{
    float2* x = A;
    float2* y = B;
    for (int s = 0; s < 6; s++) {
        const int Ns = 1 << (2 * s);
        const float inv = 1.0f / (float)(Ns << 2);
        #pragma unroll
        for (int q = 0; q < 4; q++) {
            int jj = t + (q << 8);          // 0..1023
            int jm = jj & (Ns - 1);
            float ang = (SIGN * 6.283185307179586f) * (float)jm * inv;
            float sn, cs;
            __sincosf(ang, &sn, &cs);
            float2 w1 = make_float2(cs, sn);
            float2 w2 = cmul(w1, w1);
            float2 w3 = cmul(w2, w1);
            float2 v0 = x[jj];
            float2 v1 = cmul(x[jj + 1024], w1);
            float2 v2 = cmul(x[jj + 2048], w2);
            float2 v3 = cmul(x[jj + 3072], w3);
            float2 t0 = cadd(v0, v2), t1 = csub(v0, v2);
            float2 t2 = cadd(v1, v3), t3 = csub(v1, v3);
            float2 V0 = cadd(t0, t2), V2 = csub(t0, t2);
            float2 jt3;   // SIGN<0: -i*t3 ; SIGN>0: +i*t3
            if (SIGN < 0) { jt3.x =  t3.y; jt3.y = -t3.x; }
            else          { jt3.x = -t3.y; jt3.y =  t3.x; }
            float2 V1 = cadd(t1, jt3), V3 = csub(t1, jt3);
            int idx = ((jj - jm) << 2) + jm;
            y[idx]          = V0;
            y[idx + Ns]     = V1;
            y[idx + 2 * Ns] = V2;
            y[idx + 3 * Ns] = V3;
        }
        __syncthreads();
        float2* tmp = x; x = y; y = tmp;
    }
    // 6 swaps -> result back in A
}

__global__ __launch_bounds__(256)
void fft_conv(const u16* __restrict__ vt, const float2* __restrict__ gate,
              u16* __restrict__ yt)
{
    __shared__ float2 bufA[4096];
    __shared__ float2 bufB[4096];
    const int blk = blockIdx.x;
    const int b = blk >> 9;
    const int rem = blk & 511;                     // h*32 + p
    const size_t rowoff = ((size_t)b * 1024 + rem * 2) * 4096;
    const u16* r0 = vt + rowoff;
    const u16* r1 = r0 + 4096;
    const int t = threadIdx.x;

    for (int q = 0; q < 16; q++) {
        int n = (q << 8) + t;
        bufA[n] = make_float2(bf2f(r0[n]), bf2f(r1[n]));
    }
    __syncthreads();

    fft6<-1>(bufA, bufB, t);

    const float2* grow = gate + (size_t)((b << 4) | (rem >> 5)) * NFFT;
    for (int q = 0; q < 16; q++) {
        int k = (q << 8) + t;
        float2 g;
        if (k <= 2048) g = grow[k];
        else { float2 gg = grow[4096 - k]; g.x = gg.x; g.y = -gg.y; }
        float2 z = bufA[k];
        bufA[k] = make_float2(z.x * g.x - z.y * g.y, z.x * g.y + z.y * g.x);
    }
    __syncthreads();

    fft6<1>(bufA, bufB, t);

    u16* o0 = yt + rowoff;
    u16* o1 = o0 + 4096;
    for (int q = 0; q < 16; q++) {
        int n = (q << 8) + t;
        float2 zz = bufA[n];
        o0[n] = f2bf(zz.x);
        o1[n] = f2bf(zz.y);
    }
}

// ---------------------------------------------------------------------------
// Kernel 6: (b, E, N) bf16 -> (b, N, E) bf16 transpose, 64x64 LDS tiles
// ---------------------------------------------------------------------------
__global__ __launch_bounds__(256)
void transpose_bn(const u16* __restrict__ in, u16* __restrict__ out)
{
    __shared__ u32 tile[64 * 65];
    const int b  = blockIdx.z;
    const int j0 = blockIdx.y << 6;
    const int n0 = blockIdx.x << 6;
    const int t  = threadIdx.x;
    #pragma unroll
    for (int i2 = 0; i2 < 16; i2++) {
        int el = (i2 << 8) + t;
        int jr = el >> 6, nc = el & 63;
        tile[jr * 65 + nc] = in[((size_t)b * 1024 + j0 + jr) * 4096 + n0 + nc];
    }
    __syncthreads();
    #pragma unroll
    for (int i2 = 0; i2 < 16; i2++) {
        int el = (i2 << 8) + t;
        int nr = el >> 6, jc = el & 63;
        out[((size_t)b * 4096 + n0 + nr) * 1024 + j0 + jc] = (u16)tile[jc * 65 + nr];
    }
}

// ---------------------------------------------------------------------------
extern "C" void kernel_launch(void* const* d_in, const int* in_sizes, int n_in,
                              void* d_out, int out_size, void* d_ws, size_t ws_size,
                              hipStream_t stream)
{
    (void)in_sizes; (void)n_in; (void)out_size; (void)ws_size;
    const float* x    = (const float*)d_in[0];
    // d_in[1] = positions (arange(N): identity gather, unused)
    const float* Wq   = (const float*)d_in[2];
    const float* Wv   = (const float*)d_in[3];
    const float* Wo   = (const float*)d_in[4];
    const float* ln_g = (const float*)d_in[5];
    const float* ln_b = (const float*)d_in[6];
    const float* w1   = (const float*)d_in[7];
    const float* b1   = (const float*)d_in[8];
    const float* w2   = (const float*)d_in[9];
    const float* b2   = (const float*)d_in[10];

    char* ws = (char*)d_ws;
    size_t off = 0;
    auto carve = [&](size_t bytes) -> char* {
        char* p = ws + off;
        off += (bytes + 255) & ~(size_t)255;
        return p;
    };
    u16*   x_bf  = (u16*)carve((size_t)B_ * N_ * E_ * 2);   // later reused as yt
    u16*   vt    = (u16*)carve((size_t)B_ * N_ * E_ * 2);   // later reused as ybt
    u16*   Wv_bf = (u16*)carve((size_t)E_ * E_ * 2);
    u16*   Wo_bf = (u16*)carve((size_t)E_ * E_ * 2);
    float* xbar  = (float*)carve((size_t)B_ * E_ * 4);
    float* gate  = (float*)carve((size_t)B_ * H_ * NFFT * 8);
    u16* yt  = x_bf;   // x_bf dead after GEMM1
    u16* ybt = vt;     // vt dead after FFT

    hipMemsetAsync(xbar, 0, (size_t)B_ * E_ * 4, stream);
    conv_x_kernel<<<dim3(64, B_), 256, 0, stream>>>(x, x_bf, xbar);
    convw_kernel<<<dim3(1024), 256, 0, stream>>>(Wv, Wv_bf, 262144);
    convw_kernel<<<dim3(1024), 256, 0, stream>>>(Wo, Wo_bf, 262144);
    gate_kernel<<<dim3(128), 256, 0, stream>>>(xbar, Wq, ln_g, ln_b, w1, b1, w2, b2, gate);
    // v^T[b, e, n] = sum_k Wv[e,k] * x[b,n,k]
    gemm_bt<1><<<dim3(256, 8), 256, 0, stream>>>(Wv_bf, x_bf, vt, 1024, 32768, 1024);
    // y^T = ifft(gate * fft(v^T)) along n, packed channel pairs
    fft_conv<<<dim3(4096), 256, 0, stream>>>(vt, (const float2*)gate, yt);
    // y^T -> y (b, n, e)
    transpose_bn<<<dim3(64, 16, B_), 256, 0, stream>>>(yt, ybt);
    // out = y @ Wo^T
    gemm_bt<0><<<dim3(8, 256), 256, 0, stream>>>(ybt, Wo_bf, d_out, 32768, 1024, 1024);
}

// Round 3
// 560.442 us; speedup vs baseline: 1.1330x; 1.1330x over previous
//
#include <hip/hip_runtime.h>
#include <cstdint>

#define B_   8
#define N_   4096
#define E_   1024
#define H_   16
#define NFFT 2049

typedef unsigned short u16;
typedef unsigned int   u32;
typedef __attribute__((ext_vector_type(4))) float f32x4;
typedef __attribute__((ext_vector_type(8))) short short8;

__device__ __forceinline__ u16 f2bf(float f) {
    u32 u = __builtin_bit_cast(u32, f);
    u += 0x7fffu + ((u >> 16) & 1u);
    return (u16)(u >> 16);
}
__device__ __forceinline__ float bf2f(u16 h) {
    u32 u = ((u32)h) << 16;
    return __builtin_bit_cast(float, u);
}

// async global->LDS, 16B per lane, lane i lands at ldsbase + i*16
__device__ __forceinline__ void gload16(const void* g, void* l) {
    __builtin_amdgcn_global_load_lds(
        (const __attribute__((address_space(1))) void*)(uintptr_t)g,
        (__attribute__((address_space(3))) void*)(u32)(uintptr_t)l,
        16, 0, 0);
}

// ---------------------------------------------------------------------------
// Kernel 1: x f32 -> bf16, fused column-mean partial sums (atomics into xbar)
// ---------------------------------------------------------------------------
__global__ __launch_bounds__(256)
void conv_x_kernel(const float* __restrict__ x, u16* __restrict__ xbf,
                   float* __restrict__ xbar)
{
    const int b  = blockIdx.y;
    const int n0 = blockIdx.x * 64;
    const int t  = threadIdx.x;
    const float4* src = (const float4*)(x + ((size_t)(b * N_ + n0)) * E_) + t;
    u16* dst = xbf + ((size_t)(b * N_ + n0)) * E_ + t * 4;
    float4 s = make_float4(0.f, 0.f, 0.f, 0.f);
    for (int r = 0; r < 64; r++) {
        float4 v = src[r * 256];
        s.x += v.x; s.y += v.y; s.z += v.z; s.w += v.w;
        *(ushort4*)(dst + (size_t)r * E_) =
            make_ushort4(f2bf(v.x), f2bf(v.y), f2bf(v.z), f2bf(v.w));
    }
    float* xb = xbar + b * E_ + t * 4;
    atomicAdd(xb + 0, s.x); atomicAdd(xb + 1, s.y);
    atomicAdd(xb + 2, s.z); atomicAdd(xb + 3, s.w);
}

// ---------------------------------------------------------------------------
// Kernel 2: f32 -> bf16 weight convert
// ---------------------------------------------------------------------------
__global__ __launch_bounds__(256)
void convw_kernel(const float* __restrict__ w, u16* __restrict__ wbf, int n4)
{
    int i = blockIdx.x * 256 + threadIdx.x;
    if (i >= n4) return;
    float4 v = ((const float4*)w)[i];
    *(ushort4*)(wbf + (size_t)i * 4) =
        make_ushort4(f2bf(v.x), f2bf(v.y), f2bf(v.z), f2bf(v.w));
}

// ---------------------------------------------------------------------------
// Kernel 3: gate MLP (unchanged, verified)
// ---------------------------------------------------------------------------
__global__ __launch_bounds__(256)
void gate_kernel(const float* __restrict__ xbar, const float* __restrict__ Wq,
                 const float* __restrict__ ln_g, const float* __restrict__ ln_b,
                 const float* __restrict__ w1,   const float* __restrict__ b1,
                 const float* __restrict__ w2,   const float* __restrict__ b2,
                 float* __restrict__ gate)
{
    const int bh = blockIdx.x;
    const int b = bh >> 4, h = bh & 15;
    const int t = threadIdx.x;
    __shared__ float s_x[1024];
    __shared__ float s_bq[64], s_ln[64], s_h1[64];

    for (int q = 0; q < 4; q++)
        s_x[(q << 8) + t] = xbar[b * 1024 + (q << 8) + t] * (1.0f / 4096.0f);
    __syncthreads();

    {
        const int d = t >> 2, part = t & 3;
        const float* wrow = Wq + (size_t)(h * 64 + d) * 1024 + part * 256;
        const float* xr = s_x + part * 256;
        float sum = 0.f;
        #pragma unroll 8
        for (int e = 0; e < 256; e++) sum += wrow[e] * xr[e];
        sum += __shfl_xor(sum, 1);
        sum += __shfl_xor(sum, 2);
        if (part == 0) s_bq[d] = sum;
    }
    __syncthreads();

    if (t < 64) {
        float v = s_bq[t];
        float s = v;
        #pragma unroll
        for (int m = 1; m < 64; m <<= 1) s += __shfl_xor(s, m);
        float mu = s * (1.0f / 64.0f);
        float dv = v - mu;
        float vv = dv * dv;
        #pragma unroll
        for (int m = 1; m < 64; m <<= 1) vv += __shfl_xor(vv, m);
        float var = vv * (1.0f / 64.0f);
        s_ln[t] = dv * rsqrtf(var + 1e-5f) * ln_g[t] + ln_b[t];
    }
    __syncthreads();

    {
        const int j = t >> 2, part = t & 3;
        const float* wrow = w1 + j * 64 + part * 16;
        const float* lr = s_ln + part * 16;
        float sum = 0.f;
        #pragma unroll
        for (int d2 = 0; d2 < 16; d2++) sum += wrow[d2] * lr[d2];
        sum += __shfl_xor(sum, 1);
        sum += __shfl_xor(sum, 2);
        if (part == 0) {
            float z = sum + b1[j];
            s_h1[j] = z / (1.0f + __expf(-z));
        }
    }
    __syncthreads();

    float* grow = gate + (size_t)bh * (2 * NFFT);
    for (int o = t; o < 2 * NFFT; o += 256) {
        const float4* wrow = (const float4*)(w2 + (size_t)o * 64);
        float sum = 0.f;
        #pragma unroll
        for (int d4 = 0; d4 < 16; d4++) {
            float4 wv = wrow[d4];
            sum += wv.x * s_h1[d4 * 4]     + wv.y * s_h1[d4 * 4 + 1]
                 + wv.z * s_h1[d4 * 4 + 2] + wv.w * s_h1[d4 * 4 + 3];
        }
        float gv = (sum + b2[o]) * (1.0f / 4096.0f);
        if (o == 1 || o == 2 * NFFT - 1) gv = 0.0f;
        grow[o] = gv;
    }
}

// ---------------------------------------------------------------------------
// Kernel 4: bf16 MFMA GEMM (m97 structure: global_load_lds + 2 barriers/K-step)
// 128x128 tile, BK=32, 4 waves, XCD-swizzled 1D grid.
// ---------------------------------------------------------------------------
template<int OUTMODE>
__global__ __launch_bounds__(256)
void gemm_bt(const u16* __restrict__ A, const u16* __restrict__ BT,
             void* __restrict__ Cv, int M, int N, int K,
             int nbx_mask, int nbx_shift)
{
    __shared__ __align__(16) u16 lA[128 * 32];
    __shared__ __align__(16) u16 lB[128 * 32];
    const int tid = threadIdx.x;
    const int w = tid >> 6, l = tid & 63;
    const int nwg = gridDim.x;
    const int q = nwg >> 3;
    const int bid = blockIdx.x;
    const int swz = (bid & 7) * q + (bid >> 3);   // bijective: nwg % 8 == 0
    const int bx = swz & nbx_mask, by = swz >> nbx_shift;
    const int m0 = by * 128, n0 = bx * 128;
    const int wr = (w >> 1) * 64, wc = (w & 1) * 64;
    const int srow = w * 16 + (l >> 2);
    const int scol = (l & 3) * 8;
    const u16* ga = A  + (size_t)(m0 + srow) * K + scol;
    const u16* gb = BT + (size_t)(n0 + srow) * K + scol;
    u16* lAw0 = lA + w * 512;
    u16* lAw1 = lA + 2048 + w * 512;
    u16* lBw0 = lB + w * 512;
    u16* lBw1 = lB + 2048 + w * 512;
    f32x4 acc[4][4] = {};

    for (int k0 = 0; k0 < K; k0 += 32) {
        __syncthreads();
        gload16(ga + k0,                   lAw0);
        gload16(ga + (size_t)64 * K + k0,  lAw1);
        gload16(gb + k0,                   lBw0);
        gload16(gb + (size_t)64 * K + k0,  lBw1);
        __syncthreads();   // compiler emits vmcnt(0) drain before barrier
        short8 af[4], bfr[4];
        #pragma unroll
        for (int i = 0; i < 4; i++) {
            af[i]  = *(const short8*)((char*)lA + (wr + i * 16 + (l & 15)) * 64 + (l >> 4) * 16);
            bfr[i] = *(const short8*)((char*)lB + (wc + i * 16 + (l & 15)) * 64 + (l >> 4) * 16);
        }
        #pragma unroll
        for (int i = 0; i < 4; i++)
            #pragma unroll
            for (int j2 = 0; j2 < 4; j2++)
                asm("v_mfma_f32_16x16x32_bf16 %0, %1, %2, %0"
                    : "+v"(acc[i][j2]) : "v"(af[i]), "v"(bfr[j2]));
    }

    const int fr = (l >> 4) * 4;
    const int fc = l & 15;
    if (OUTMODE == 0) {
        float* C = (float*)Cv;
        #pragma unroll
        for (int i = 0; i < 4; i++) {
            int m = m0 + wr + i * 16 + fr;
            #pragma unroll
            for (int j2 = 0; j2 < 4; j2++) {
                int gn = n0 + wc + j2 * 16 + fc;
                #pragma unroll
                for (int r = 0; r < 4; r++)
                    C[(size_t)(m + r) * N + gn] = acc[i][j2][r];
            }
        }
    } else {
        u16* Cb = (u16*)Cv;
        #pragma unroll
        for (int i = 0; i < 4; i++) {
            int m = m0 + wr + i * 16 + fr;
            #pragma unroll
            for (int j2 = 0; j2 < 4; j2++) {
                int gn = n0 + wc + j2 * 16 + fc;
                int bb = gn >> 12, nin = gn & 4095;
                size_t base = ((size_t)bb << 22) + (size_t)nin;
                #pragma unroll
                for (int r = 0; r < 4; r++)
                    Cb[base + (size_t)(m + r) * 4096] = f2bf(acc[i][j2][r]);
            }
        }
    }
}

// ---------------------------------------------------------------------------
// Kernel 5: packed-pair FFT conv, register radix-16 (4096 = 16^3).
// One block (256 thr) per (b, d-pair). Single padded 36KB LDS buffer.
// ---------------------------------------------------------------------------
__device__ __forceinline__ float2 cmul(float2 a, float2 b) {
    return make_float2(a.x * b.x - a.y * b.y, a.x * b.y + a.y * b.x);
}
__device__ __forceinline__ float2 cadd(float2 a, float2 b) {
    return make_float2(a.x + b.x, a.y + b.y);
}
__device__ __forceinline__ float2 csub(float2 a, float2 b) {
    return make_float2(a.x - b.x, a.y - b.y);
}
__device__ __forceinline__ float2 cmulc(float2 z, float wr, float wi) {
    return make_float2(z.x * wr - z.y * wi, z.x * wi + z.y * wr);
}

// 16-pt DFT in registers, X[k] = sum_j r[j] * e^{SGN*2pi*i*jk/16}
template<int SGN>
__device__ __forceinline__ void dft16(float2* r)
{
    const float s = (float)SGN;
    const float C1 = 0.9238795325112867f;
    const float S1 = 0.3826834323650898f;
    const float R2 = 0.7071067811865476f;
    float2 Bv[16];
    #pragma unroll
    for (int j0 = 0; j0 < 4; j0++) {
        float2 a = r[j0], b = r[4 + j0], c = r[8 + j0], d = r[12 + j0];
        float2 t0 = cadd(a, c), t1 = csub(a, c);
        float2 t2 = cadd(b, d), t3 = csub(b, d);
        float2 rt = make_float2(-s * t3.y, s * t3.x);
        Bv[j0 * 4 + 0] = cadd(t0, t2);
        Bv[j0 * 4 + 1] = cadd(t1, rt);
        Bv[j0 * 4 + 2] = csub(t0, t2);
        Bv[j0 * 4 + 3] = csub(t1, rt);
    }
    Bv[5]  = cmulc(Bv[5],  C1,  s * S1);
    Bv[6]  = cmulc(Bv[6],  R2,  s * R2);
    Bv[7]  = cmulc(Bv[7],  S1,  s * C1);
    Bv[9]  = cmulc(Bv[9],  R2,  s * R2);
    Bv[10] = make_float2(-s * Bv[10].y, s * Bv[10].x);
    Bv[11] = cmulc(Bv[11], -R2,  s * R2);
    Bv[13] = cmulc(Bv[13],  S1,  s * C1);
    Bv[14] = cmulc(Bv[14], -R2,  s * R2);
    Bv[15] = cmulc(Bv[15], -C1, -s * S1);
    #pragma unroll
    for (int k0 = 0; k0 < 4; k0++) {
        float2 a = Bv[k0], b = Bv[4 + k0], c = Bv[8 + k0], d = Bv[12 + k0];
        float2 t0 = cadd(a, c), t1 = csub(a, c);
        float2 t2 = cadd(b, d), t3 = csub(b, d);
        float2 rt = make_float2(-s * t3.y, s * t3.x);
        r[k0]      = cadd(t0, t2);
        r[k0 + 4]  = cadd(t1, rt);
        r[k0 + 8]  = csub(t0, t2);
        r[k0 + 12] = csub(t1, rt);
    }
}

// r[m] *= e^{i*ang*m}, m=0..15 (iterated powers; |ang| < 0.4 rad here)
__device__ __forceinline__ void twiddle_iter(float2* r, float ang)
{
    float sn, cs;
    __sincosf(ang, &sn, &cs);
    float2 w = make_float2(cs, sn);
    float2 tw = w;
    #pragma unroll
    for (int m = 1; m < 16; m++) {
        r[m] = cmul(r[m], tw);
        tw = cmul(tw, w);
    }
}

__global__ __launch_bounds__(256, 4)
void fft_conv(const u16* __restrict__ vt, const float2* __restrict__ gate,
              u16* __restrict__ yt)
{
    // padded layout: element i lives at S[i + 2*(i>>4)]  (36 KB)
    __shared__ float2 S[4608];
    const int blk = blockIdx.x;
    const int b = blk >> 9;
    const int rem = blk & 511;
    const size_t rowoff = ((size_t)b * 1024 + rem * 2) * 4096;
    const u16* r0 = vt + rowoff;
    const u16* r1 = r0 + 4096;
    const int t = threadIdx.x;
    const int k1 = t >> 4, j16 = t & 15;

    float2 r[16];
    // load: r[j] = z[j*256 + t]  (lane-coalesced)
    #pragma unroll
    for (int j = 0; j < 16; j++) {
        int n = j * 256 + t;
        r[j] = make_float2(bf2f(r0[n]), bf2f(r1[n]));
    }
    // fwd stage 1: DFT over n1 (stride 256), twiddle W4096^{-t*k}
    dft16<-1>(r);
    twiddle_iter(r, -6.283185307179586f * (float)t * (1.0f / 4096.0f));
    #pragma unroll
    for (int m = 0; m < 16; m++)
        S[m * 288 + t + 2 * (t >> 4)] = r[m];
    __syncthreads();

    // fwd stage 2: thread (k1, n2''=j16), DFT over n1'' (stride 16)
    {
        int base = k1 * 288 + j16;
        #pragma unroll
        for (int j = 0; j < 16; j++) r[j] = S[base + 18 * j];
        dft16<-1>(r);
        twiddle_iter(r, -6.283185307179586f * (float)j16 * (1.0f / 256.0f));
        #pragma unroll
        for (int m = 0; m < 16; m++) S[base + 18 * m] = r[m];
    }

    // gate loads issued early (L2-resident, hides latency over the barrier)
    const int d = k1 + (j16 << 4);
    const float2* grow = gate + (size_t)((b << 4) | (rem >> 5)) * NFFT;
    float2 g[16];
    #pragma unroll
    for (int j = 0; j < 16; j++) {
        int k = d + (j << 8);
        bool hi = k > 2048;
        int idx = hi ? 4096 - k : k;
        float2 gg = grow[idx];
        g[j] = make_float2(gg.x, hi ? -gg.y : gg.y);
    }
    __syncthreads();

    // fwd stage 3 (contiguous b128 reads) + gate + inv stage A, thread (k1,k1'=j16)
    {
        int base = k1 * 288 + j16 * 18;
        #pragma unroll
        for (int j = 0; j < 16; j += 2) {
            float4 v = *(const float4*)&S[base + j];
            r[j]     = make_float2(v.x, v.y);
            r[j + 1] = make_float2(v.z, v.w);
        }
        dft16<-1>(r);                       // -> X[d + 256*k2']
        #pragma unroll
        for (int j = 0; j < 16; j++) r[j] = cmul(r[j], g[j]);
        dft16<1>(r);                        // inv DFT over k2'
        twiddle_iter(r, 6.283185307179586f * (float)j16 * (1.0f / 256.0f));
        #pragma unroll
        for (int m = 0; m < 16; m += 2)
            *(float4*)&S[base + m] = make_float4(r[m].x, r[m].y, r[m + 1].x, r[m + 1].y);
    }
    __syncthreads();

    // inv stage B: thread (k1, n2''=j16), DFT over k1' (stride 16)
    {
        int base = k1 * 288 + j16;
        #pragma unroll
        for (int j = 0; j < 16; j++) r[j] = S[base + 18 * j];
        dft16<1>(r);
        #pragma unroll
        for (int m = 0; m < 16; m++) S[base + 18 * m] = r[m];
    }
    __syncthreads();

    // inv stage C: twiddle W4096^{+t*k1} then DFT over k1 -> y[n1*256 + t]
    #pragma unroll
    for (int j = 0; j < 16; j++) r[j] = S[j * 288 + t + 2 * (t >> 4)];
    twiddle_iter(r, 6.283185307179586f * (float)t * (1.0f / 4096.0f));
    dft16<1>(r);

    u16* o0 = yt + rowoff;
    u16* o1 = o0 + 4096;
    #pragma unroll
    for (int m = 0; m < 16; m++) {
        int n = m * 256 + t;
        o0[n] = f2bf(r[m].x);
        o1[n] = f2bf(r[m].y);
    }
}

// ---------------------------------------------------------------------------
// Kernel 6: (b, E, N) bf16 -> (b, N, E) bf16 transpose (unchanged)
// ---------------------------------------------------------------------------
__global__ __launch_bounds__(256)
void transpose_bn(const u16* __restrict__ in, u16* __restrict__ out)
{
    __shared__ u32 tile[64 * 65];
    const int b  = blockIdx.z;
    const int j0 = blockIdx.y << 6;
    const int n0 = blockIdx.x << 6;
    const int t  = threadIdx.x;
    #pragma unroll
    for (int i2 = 0; i2 < 16; i2++) {
        int el = (i2 << 8) + t;
        int jr = el >> 6, nc = el & 63;
        tile[jr * 65 + nc] = in[((size_t)b * 1024 + j0 + jr) * 4096 + n0 + nc];
    }
    __syncthreads();
    #pragma unroll
    for (int i2 = 0; i2 < 16; i2++) {
        int el = (i2 << 8) + t;
        int nr = el >> 6, jc = el & 63;
        out[((size_t)b * 4096 + n0 + nr) * 1024 + j0 + jc] = (u16)tile[jc * 65 + nr];
    }
}

// ---------------------------------------------------------------------------
extern "C" void kernel_launch(void* const* d_in, const int* in_sizes, int n_in,
                              void* d_out, int out_size, void* d_ws, size_t ws_size,
                              hipStream_t stream)
{
    (void)in_sizes; (void)n_in; (void)out_size; (void)ws_size;
    const float* x    = (const float*)d_in[0];
    const float* Wq   = (const float*)d_in[2];
    const float* Wv   = (const float*)d_in[3];
    const float* Wo   = (const float*)d_in[4];
    const float* ln_g = (const float*)d_in[5];
    const float* ln_b = (const float*)d_in[6];
    const float* w1   = (const float*)d_in[7];
    const float* b1   = (const float*)d_in[8];
    const float* w2   = (const float*)d_in[9];
    const float* b2   = (const float*)d_in[10];

    char* ws = (char*)d_ws;
    size_t off = 0;
    auto carve = [&](size_t bytes) -> char* {
        char* p = ws + off;
        off += (bytes + 255) & ~(size_t)255;
        return p;
    };
    u16*   x_bf  = (u16*)carve((size_t)B_ * N_ * E_ * 2);
    u16*   vt    = (u16*)carve((size_t)B_ * N_ * E_ * 2);
    u16*   Wv_bf = (u16*)carve((size_t)E_ * E_ * 2);
    u16*   Wo_bf = (u16*)carve((size_t)E_ * E_ * 2);
    float* xbar  = (float*)carve((size_t)B_ * E_ * 4);
    float* gate  = (float*)carve((size_t)B_ * H_ * NFFT * 8);
    u16* yt  = x_bf;
    u16* ybt = vt;

    hipMemsetAsync(xbar, 0, (size_t)B_ * E_ * 4, stream);
    conv_x_kernel<<<dim3(64, B_), 256, 0, stream>>>(x, x_bf, xbar);
    convw_kernel<<<dim3(1024), 256, 0, stream>>>(Wv, Wv_bf, 262144);
    convw_kernel<<<dim3(1024), 256, 0, stream>>>(Wo, Wo_bf, 262144);
    gate_kernel<<<dim3(128), 256, 0, stream>>>(xbar, Wq, ln_g, ln_b, w1, b1, w2, b2, gate);
    // v^T[b, e, n]
    gemm_bt<1><<<dim3(2048), 256, 0, stream>>>(Wv_bf, x_bf, vt, 1024, 32768, 1024, 255, 8);
    fft_conv<<<dim3(4096), 256, 0, stream>>>(vt, (const float2*)gate, yt);
    transpose_bn<<<dim3(64, 16, B_), 256, 0, stream>>>(yt, ybt);
    gemm_bt<0><<<dim3(2048), 256, 0, stream>>>(ybt, Wo_bf, d_out, 32768, 1024, 1024, 7, 3);
}

// Round 5
// 536.241 us; speedup vs baseline: 1.1841x; 1.0451x over previous
//
#include <hip/hip_runtime.h>
#include <cstdint>

#define B_   8
#define N_   4096
#define E_   1024
#define H_   16
#define NFFT 2049

typedef unsigned short u16;
typedef unsigned int   u32;
typedef __attribute__((ext_vector_type(4))) float f32x4;
typedef __attribute__((ext_vector_type(8))) short short8;

__device__ __forceinline__ u16 f2bf(float f) {
    u32 u = __builtin_bit_cast(u32, f);
    u += 0x7fffu + ((u >> 16) & 1u);
    return (u16)(u >> 16);
}
__device__ __forceinline__ float bf2f(u16 h) {
    u32 u = ((u32)h) << 16;
    return __builtin_bit_cast(float, u);
}

// async global->LDS, 16B per lane, lane i lands at ldsbase + i*16
__device__ __forceinline__ void gload16(const void* g, void* l) {
    __builtin_amdgcn_global_load_lds(
        (const __attribute__((address_space(1))) void*)(uintptr_t)g,
        (__attribute__((address_space(3))) void*)(u32)(uintptr_t)l,
        16, 0, 0);
}

// ---------------------------------------------------------------------------
// Kernel 1: x f32 -> bf16, fused column-mean partial sums (atomics into xbar)
// ---------------------------------------------------------------------------
__global__ __launch_bounds__(256)
void conv_x_kernel(const float* __restrict__ x, u16* __restrict__ xbf,
                   float* __restrict__ xbar)
{
    const int b  = blockIdx.y;
    const int n0 = blockIdx.x * 64;
    const int t  = threadIdx.x;
    const float4* src = (const float4*)(x + ((size_t)(b * N_ + n0)) * E_) + t;
    u16* dst = xbf + ((size_t)(b * N_ + n0)) * E_ + t * 4;
    float4 s = make_float4(0.f, 0.f, 0.f, 0.f);
    for (int r = 0; r < 64; r++) {
        float4 v = src[r * 256];
        s.x += v.x; s.y += v.y; s.z += v.z; s.w += v.w;
        *(ushort4*)(dst + (size_t)r * E_) =
            make_ushort4(f2bf(v.x), f2bf(v.y), f2bf(v.z), f2bf(v.w));
    }
    float* xb = xbar + b * E_ + t * 4;
    atomicAdd(xb + 0, s.x); atomicAdd(xb + 1, s.y);
    atomicAdd(xb + 2, s.z); atomicAdd(xb + 3, s.w);
}

// ---------------------------------------------------------------------------
// Kernel 2: f32 -> bf16 weight convert
// ---------------------------------------------------------------------------
__global__ __launch_bounds__(256)
void convw_kernel(const float* __restrict__ w, u16* __restrict__ wbf, int n4)
{
    int i = blockIdx.x * 256 + threadIdx.x;
    if (i >= n4) return;
    float4 v = ((const float4*)w)[i];
    *(ushort4*)(wbf + (size_t)i * 4) =
        make_ushort4(f2bf(v.x), f2bf(v.y), f2bf(v.z), f2bf(v.w));
}

// ---------------------------------------------------------------------------
// Kernel 3: gate MLP (unchanged, verified)
// ---------------------------------------------------------------------------
__global__ __launch_bounds__(256)
void gate_kernel(const float* __restrict__ xbar, const float* __restrict__ Wq,
                 const float* __restrict__ ln_g, const float* __restrict__ ln_b,
                 const float* __restrict__ w1,   const float* __restrict__ b1,
                 const float* __restrict__ w2,   const float* __restrict__ b2,
                 float* __restrict__ gate)
{
    const int bh = blockIdx.x;
    const int b = bh >> 4, h = bh & 15;
    const int t = threadIdx.x;
    __shared__ float s_x[1024];
    __shared__ float s_bq[64], s_ln[64], s_h1[64];

    for (int q = 0; q < 4; q++)
        s_x[(q << 8) + t] = xbar[b * 1024 + (q << 8) + t] * (1.0f / 4096.0f);
    __syncthreads();

    {
        const int d = t >> 2, part = t & 3;
        const float* wrow = Wq + (size_t)(h * 64 + d) * 1024 + part * 256;
        const float* xr = s_x + part * 256;
        float sum = 0.f;
        #pragma unroll 8
        for (int e = 0; e < 256; e++) sum += wrow[e] * xr[e];
        sum += __shfl_xor(sum, 1);
        sum += __shfl_xor(sum, 2);
        if (part == 0) s_bq[d] = sum;
    }
    __syncthreads();

    if (t < 64) {
        float v = s_bq[t];
        float s = v;
        #pragma unroll
        for (int m = 1; m < 64; m <<= 1) s += __shfl_xor(s, m);
        float mu = s * (1.0f / 64.0f);
        float dv = v - mu;
        float vv = dv * dv;
        #pragma unroll
        for (int m = 1; m < 64; m <<= 1) vv += __shfl_xor(vv, m);
        float var = vv * (1.0f / 64.0f);
        s_ln[t] = dv * rsqrtf(var + 1e-5f) * ln_g[t] + ln_b[t];
    }
    __syncthreads();

    {
        const int j = t >> 2, part = t & 3;
        const float* wrow = w1 + j * 64 + part * 16;
        const float* lr = s_ln + part * 16;
        float sum = 0.f;
        #pragma unroll
        for (int d2 = 0; d2 < 16; d2++) sum += wrow[d2] * lr[d2];
        sum += __shfl_xor(sum, 1);
        sum += __shfl_xor(sum, 2);
        if (part == 0) {
            float z = sum + b1[j];
            s_h1[j] = z / (1.0f + __expf(-z));
        }
    }
    __syncthreads();

    float* grow = gate + (size_t)bh * (2 * NFFT);
    for (int o = t; o < 2 * NFFT; o += 256) {
        const float4* wrow = (const float4*)(w2 + (size_t)o * 64);
        float sum = 0.f;
        #pragma unroll
        for (int d4 = 0; d4 < 16; d4++) {
            float4 wv = wrow[d4];
            sum += wv.x * s_h1[d4 * 4]     + wv.y * s_h1[d4 * 4 + 1]
                 + wv.z * s_h1[d4 * 4 + 2] + wv.w * s_h1[d4 * 4 + 3];
        }
        float gv = (sum + b2[o]) * (1.0f / 4096.0f);
        if (o == 1 || o == 2 * NFFT - 1) gv = 0.0f;
        grow[o] = gv;
    }
}

// ---------------------------------------------------------------------------
// Kernel 4: bf16 MFMA GEMM (m97 structure: global_load_lds + 2 barriers/K-step)
// 128x128 tile, BK=32, 4 waves, XCD-swizzled 1D grid.
// SWAP=1: by = swz&7 (fastest) -> the 8 readers of each 128-wide B-panel are
//         co-resident per XCD (L2-hit); use when N-dim operand is the big one
//         and nby == 8.  SWAP=0: bx = swz&7 fastest (big A operand, nbx == 8).
// LDS col16 of each row XOR-permuted by (row&3): staged via pre-swizzled
// global source col (involution; same per-wave address set -> coalescing
// preserved), read back with the same XOR. Cuts 8-way ds_read conflict to 4.
// ---------------------------------------------------------------------------
template<int OUTMODE, int SWAP>
__global__ __launch_bounds__(256)
void gemm_bt(const u16* __restrict__ A, const u16* __restrict__ BT,
             void* __restrict__ Cv, int M, int N, int K)
{
    __shared__ __align__(16) u16 lA[128 * 32];
    __shared__ __align__(16) u16 lB[128 * 32];
    const int tid = threadIdx.x;
    const int w = tid >> 6, l = tid & 63;
    const int nwg = gridDim.x;
    const int q = nwg >> 3;
    const int bid = blockIdx.x;
    const int swz = (bid & 7) * q + (bid >> 3);   // bijective: nwg % 8 == 0
    const int bx = SWAP ? (swz >> 3) : (swz & 7);
    const int by = SWAP ? (swz & 7) : (swz >> 3);
    const int m0 = by * 128, n0 = bx * 128;
    const int wr = (w >> 1) * 64, wc = (w & 1) * 64;
    const int srow = w * 16 + (l >> 2);
    const int scol = ((l & 3) ^ ((l >> 2) & 3)) * 8;   // bank-swizzle source
    const u16* ga = A  + (size_t)(m0 + srow) * K + scol;
    const u16* gb = BT + (size_t)(n0 + srow) * K + scol;
    u16* lAw0 = lA + w * 512;
    u16* lAw1 = lA + 2048 + w * 512;
    u16* lBw0 = lB + w * 512;
    u16* lBw1 = lB + 2048 + w * 512;
    f32x4 acc[4][4] = {};

    for (int k0 = 0; k0 < K; k0 += 32) {
        __syncthreads();
        gload16(ga + k0,                   lAw0);
        gload16(ga + (size_t)64 * K + k0,  lAw1);
        gload16(gb + k0,                   lBw0);
        gload16(gb + (size_t)64 * K + k0,  lBw1);
        __syncthreads();   // compiler emits vmcnt(0) drain before barrier
        short8 af[4], bfr[4];
        const int c16 = ((l >> 4) ^ (l & 3)) * 16;   // (row&3) == (l&3) here
        #pragma unroll
        for (int i = 0; i < 4; i++) {
            af[i]  = *(const short8*)((char*)lA + (wr + i * 16 + (l & 15)) * 64 + c16);
            bfr[i] = *(const short8*)((char*)lB + (wc + i * 16 + (l & 15)) * 64 + c16);
        }
        #pragma unroll
        for (int i = 0; i < 4; i++)
            #pragma unroll
            for (int j2 = 0; j2 < 4; j2++)
                asm("v_mfma_f32_16x16x32_bf16 %0, %1, %2, %0"
                    : "+v"(acc[i][j2]) : "v"(af[i]), "v"(bfr[j2]));
    }

    const int fr = (l >> 4) * 4;
    const int fc = l & 15;
    if (OUTMODE == 0) {
        float* C = (float*)Cv;
        #pragma unroll
        for (int i = 0; i < 4; i++) {
            int m = m0 + wr + i * 16 + fr;
            #pragma unroll
            for (int j2 = 0; j2 < 4; j2++) {
                int gn = n0 + wc + j2 * 16 + fc;
                #pragma unroll
                for (int r = 0; r < 4; r++)
                    C[(size_t)(m + r) * N + gn] = acc[i][j2][r];
            }
        }
    } else {
        u16* Cb = (u16*)Cv;
        #pragma unroll
        for (int i = 0; i < 4; i++) {
            int m = m0 + wr + i * 16 + fr;
            #pragma unroll
            for (int j2 = 0; j2 < 4; j2++) {
                int gn = n0 + wc + j2 * 16 + fc;
                int bb = gn >> 12, nin = gn & 4095;
                size_t base = ((size_t)bb << 22) + (size_t)nin;
                #pragma unroll
                for (int r = 0; r < 4; r++)
                    Cb[base + (size_t)(m + r) * 4096] = f2bf(acc[i][j2][r]);
            }
        }
    }
}

// ---------------------------------------------------------------------------
// Kernel 5: packed-pair FFT conv, register radix-16 (4096 = 16^3).
// One block (256 thr) per (b, d-pair). Single padded 36KB LDS buffer.
// ---------------------------------------------------------------------------
__device__ __forceinline__ float2 cmul(float2 a, float2 b) {
    return make_float2(a.x * b.x - a.y * b.y, a.x * b.y + a.y * b.x);
}
__device__ __forceinline__ float2 cadd(float2 a, float2 b) {
    return make_float2(a.x + b.x, a.y + b.y);
}
__device__ __forceinline__ float2 csub(float2 a, float2 b) {
    return make_float2(a.x - b.x, a.y - b.y);
}
__device__ __forceinline__ float2 cmulc(float2 z, float wr, float wi) {
    return make_float2(z.x * wr - z.y * wi, z.x * wi + z.y * wr);
}

// 16-pt DFT in registers, X[k] = sum_j r[j] * e^{SGN*2pi*i*jk/16}
template<int SGN>
__device__ __forceinline__ void dft16(float2* r)
{
    const float s = (float)SGN;
    const float C1 = 0.9238795325112867f;
    const float S1 = 0.3826834323650898f;
    const float R2 = 0.7071067811865476f;
    float2 Bv[16];
    #pragma unroll
    for (int j0 = 0; j0 < 4; j0++) {
        float2 a = r[j0], b = r[4 + j0], c = r[8 + j0], d = r[12 + j0];
        float2 t0 = cadd(a, c), t1 = csub(a, c);
        float2 t2 = cadd(b, d), t3 = csub(b, d);
        float2 rt = make_float2(-s * t3.y, s * t3.x);
        Bv[j0 * 4 + 0] = cadd(t0, t2);
        Bv[j0 * 4 + 1] = cadd(t1, rt);
        Bv[j0 * 4 + 2] = csub(t0, t2);
        Bv[j0 * 4 + 3] = csub(t1, rt);
    }
    Bv[5]  = cmulc(Bv[5],  C1,  s * S1);
    Bv[6]  = cmulc(Bv[6],  R2,  s * R2);
    Bv[7]  = cmulc(Bv[7],  S1,  s * C1);
    Bv[9]  = cmulc(Bv[9],  R2,  s * R2);
    Bv[10] = make_float2(-s * Bv[10].y, s * Bv[10].x);
    Bv[11] = cmulc(Bv[11], -R2,  s * R2);
    Bv[13] = cmulc(Bv[13],  S1,  s * C1);
    Bv[14] = cmulc(Bv[14], -R2,  s * R2);
    Bv[15] = cmulc(Bv[15], -C1, -s * S1);
    #pragma unroll
    for (int k0 = 0; k0 < 4; k0++) {
        float2 a = Bv[k0], b = Bv[4 + k0], c = Bv[8 + k0], d = Bv[12 + k0];
        float2 t0 = cadd(a, c), t1 = csub(a, c);
        float2 t2 = cadd(b, d), t3 = csub(b, d);
        float2 rt = make_float2(-s * t3.y, s * t3.x);
        r[k0]      = cadd(t0, t2);
        r[k0 + 4]  = cadd(t1, rt);
        r[k0 + 8]  = csub(t0, t2);
        r[k0 + 12] = csub(t1, rt);
    }
}

// r[m] *= e^{i*ang*m}, m=0..15 (iterated powers; |ang| < 0.4 rad here)
__device__ __forceinline__ void twiddle_iter(float2* r, float ang)
{
    float sn, cs;
    __sincosf(ang, &sn, &cs);
    float2 w = make_float2(cs, sn);
    float2 tw = w;
    #pragma unroll
    for (int m = 1; m < 16; m++) {
        r[m] = cmul(r[m], tw);
        tw = cmul(tw, w);
    }
}

__global__ __launch_bounds__(256, 4)
void fft_conv(const u16* __restrict__ vt, const float2* __restrict__ gate,
              u16* __restrict__ yt)
{
    // padded layout: element i lives at S[i + 2*(i>>4)]  (36 KB)
    __shared__ float2 S[4608];
    const int blk = blockIdx.x;
    const int b = blk >> 9;
    const int rem = blk & 511;
    const size_t rowoff = ((size_t)b * 1024 + rem * 2) * 4096;
    const u16* r0 = vt + rowoff;
    const u16* r1 = r0 + 4096;
    const int t = threadIdx.x;
    const int k1 = t >> 4, j16 = t & 15;

    float2 r[16];
    // load: r[j] = z[j*256 + t]  (lane-coalesced)
    #pragma unroll
    for (int j = 0; j < 16; j++) {
        int n = j * 256 + t;
        r[j] = make_float2(bf2f(r0[n]), bf2f(r1[n]));
    }
    // fwd stage 1: DFT over n1 (stride 256), twiddle W4096^{-t*k}
    dft16<-1>(r);
    twiddle_iter(r, -6.283185307179586f * (float)t * (1.0f / 4096.0f));
    #pragma unroll
    for (int m = 0; m < 16; m++)
        S[m * 288 + t + 2 * (t >> 4)] = r[m];
    __syncthreads();

    // fwd stage 2: thread (k1, n2''=j16), DFT over n1'' (stride 16)
    {
        int base = k1 * 288 + j16;
        #pragma unroll
        for (int j = 0; j < 16; j++) r[j] = S[base + 18 * j];
        dft16<-1>(r);
        twiddle_iter(r, -6.283185307179586f * (float)j16 * (1.0f / 256.0f));
        #pragma unroll
        for (int m = 0; m < 16; m++) S[base + 18 * m] = r[m];
    }

    // gate loads issued early (L2-resident, hides latency over the barrier)
    const int d = k1 + (j16 << 4);
    const float2* grow = gate + (size_t)((b << 4) | (rem >> 5)) * NFFT;
    float2 g[16];
    #pragma unroll
    for (int j = 0; j < 16; j++) {
        int k = d + (j << 8);
        bool hi = k > 2048;
        int idx = hi ? 4096 - k : k;
        float2 gg = grow[idx];
        g[j] = make_float2(gg.x, hi ? -gg.y : gg.y);
    }
    __syncthreads();

    // fwd stage 3 (contiguous b128 reads) + gate + inv stage A, thread (k1,k1'=j16)
    {
        int base = k1 * 288 + j16 * 18;
        #pragma unroll
        for (int j = 0; j < 16; j += 2) {
            float4 v = *(const float4*)&S[base + j];
            r[j]     = make_float2(v.x, v.y);
            r[j + 1] = make_float2(v.z, v.w);
        }
        dft16<-1>(r);                       // -> X[d + 256*k2']
        #pragma unroll
        for (int j = 0; j < 16; j++) r[j] = cmul(r[j], g[j]);
        dft16<1>(r);                        // inv DFT over k2'
        twiddle_iter(r, 6.283185307179586f * (float)j16 * (1.0f / 256.0f));
        #pragma unroll
        for (int m = 0; m < 16; m += 2)
            *(float4*)&S[base + m] = make_float4(r[m].x, r[m].y, r[m + 1].x, r[m + 1].y);
    }
    __syncthreads();

    // inv stage B: thread (k1, n2''=j16), DFT over k1' (stride 16)
    {
        int base = k1 * 288 + j16;
        #pragma unroll
        for (int j = 0; j < 16; j++) r[j] = S[base + 18 * j];
        dft16<1>(r);
        #pragma unroll
        for (int m = 0; m < 16; m++) S[base + 18 * m] = r[m];
    }
    __syncthreads();

    // inv stage C: twiddle W4096^{+t*k1} then DFT over k1 -> y[n1*256 + t]
    #pragma unroll
    for (int j = 0; j < 16; j++) r[j] = S[j * 288 + t + 2 * (t >> 4)];
    twiddle_iter(r, 6.283185307179586f * (float)t * (1.0f / 4096.0f));
    dft16<1>(r);

    u16* o0 = yt + rowoff;
    u16* o1 = o0 + 4096;
    #pragma unroll
    for (int m = 0; m < 16; m++) {
        int n = m * 256 + t;
        o0[n] = f2bf(r[m].x);
        o1[n] = f2bf(r[m].y);
    }
}

// ---------------------------------------------------------------------------
// Kernel 6: (b, E, N) bf16 -> (b, N, E) bf16 transpose (unchanged)
// ---------------------------------------------------------------------------
__global__ __launch_bounds__(256)
void transpose_bn(const u16* __restrict__ in, u16* __restrict__ out)
{
    __shared__ u32 tile[64 * 65];
    const int b  = blockIdx.z;
    const int j0 = blockIdx.y << 6;
    const int n0 = blockIdx.x << 6;
    const int t  = threadIdx.x;
    #pragma unroll
    for (int i2 = 0; i2 < 16; i2++) {
        int el = (i2 << 8) + t;
        int jr = el >> 6, nc = el & 63;
        tile[jr * 65 + nc] = in[((size_t)b * 1024 + j0 + jr) * 4096 + n0 + nc];
    }
    __syncthreads();
    #pragma unroll
    for (int i2 = 0; i2 < 16; i2++) {
        int el = (i2 << 8) + t;
        int nr = el >> 6, jc = el & 63;
        out[((size_t)b * 4096 + n0 + nr) * 1024 + j0 + jc] = (u16)tile[jc * 65 + nr];
    }
}

// ---------------------------------------------------------------------------
extern "C" void kernel_launch(void* const* d_in, const int* in_sizes, int n_in,
                              void* d_out, int out_size, void* d_ws, size_t ws_size,
                              hipStream_t stream)
{
    (void)in_sizes; (void)n_in; (void)out_size; (void)ws_size;
    const float* x    = (const float*)d_in[0];
    const float* Wq   = (const float*)d_in[2];
    const float* Wv   = (const float*)d_in[3];
    const float* Wo   = (const float*)d_in[4];
    const float* ln_g = (const float*)d_in[5];
    const float* ln_b = (const float*)d_in[6];
    const float* w1   = (const float*)d_in[7];
    const float* b1   = (const float*)d_in[8];
    const float* w2   = (const float*)d_in[9];
    const float* b2   = (const float*)d_in[10];

    char* ws = (char*)d_ws;
    size_t off = 0;
    auto carve = [&](size_t bytes) -> char* {
        char* p = ws + off;
        off += (bytes + 255) & ~(size_t)255;
        return p;
    };
    u16*   x_bf  = (u16*)carve((size_t)B_ * N_ * E_ * 2);
    u16*   vt    = (u16*)carve((size_t)B_ * N_ * E_ * 2);
    u16*   Wv_bf = (u16*)carve((size_t)E_ * E_ * 2);
    u16*   Wo_bf = (u16*)carve((size_t)E_ * E_ * 2);
    float* xbar  = (float*)carve((size_t)B_ * E_ * 4);
    float* gate  = (float*)carve((size_t)B_ * H_ * NFFT * 8);
    u16* yt  = x_bf;
    u16* ybt = vt;

    hipMemsetAsync(xbar, 0, (size_t)B_ * E_ * 4, stream);
    conv_x_kernel<<<dim3(64, B_), 256, 0, stream>>>(x, x_bf, xbar);
    convw_kernel<<<dim3(1024), 256, 0, stream>>>(Wv, Wv_bf, 262144);
    convw_kernel<<<dim3(1024), 256, 0, stream>>>(Wo, Wo_bf, 262144);
    gate_kernel<<<dim3(128), 256, 0, stream>>>(xbar, Wq, ln_g, ln_b, w1, b1, w2, b2, gate);
    // v^T[b, e, n]  (big operand = BT = x_bf -> by-fastest ordering, SWAP=1)
    gemm_bt<1, 1><<<dim3(2048), 256, 0, stream>>>(Wv_bf, x_bf, vt, 1024, 32768, 1024);
    fft_conv<<<dim3(4096), 256, 0, stream>>>(vt, (const float2*)gate, yt);
    transpose_bn<<<dim3(64, 16, B_), 256, 0, stream>>>(yt, ybt);
    // out = y @ Wo^T  (big operand = A = ybt -> bx-fastest ordering, SWAP=0)
    gemm_bt<0, 0><<<dim3(2048), 256, 0, stream>>>(ybt, Wo_bf, d_out, 32768, 1024, 1024);
}